// Round 12
// baseline (88.177 us; speedup 1.0000x reference)
//
#include <hip/hip_runtime.h>
#include <hip/hip_bf16.h>

#define FULL_DIM 4096
#define EXPERT_DIM 1024
#define SLICE 512
#define S0 (3*SLICE)
#define P_TOK 4096
#define BATCH 4
#define NCW 32

typedef __bf16 bf16;
typedef __bf16 bf16x4 __attribute__((ext_vector_type(4)));
typedef __bf16 bf16x8 __attribute__((ext_vector_type(8)));
typedef float f32x4 __attribute__((ext_vector_type(4)));

__device__ inline void gl_lds16(const void* g, void* l) {
    __builtin_amdgcn_global_load_lds((const __attribute__((address_space(1))) void*)g,
                                     (__attribute__((address_space(3))) void*)l, 16, 0, 0);
}

__device__ inline bf16x8 cvt8(const float* src) {
    float4 a = *(const float4*)(src);
    float4 b = *(const float4*)(src + 4);
    bf16x8 w = { (bf16)a.x, (bf16)a.y, (bf16)a.z, (bf16)a.w,
                 (bf16)b.x, (bf16)b.y, (bf16)b.z, (bf16)b.w };
    return w;
}

// ============ single fused kernel: phase A (front) -> grid barrier -> phase B (QKV+aff) ============
// Phase A roles by bid: [0,ngate) gate; ngate mask; [ngate+2, +NCW) cw partials;
//   [cvbase, +24) convert W slab y=bid-cvbase (cvbase%8==0 so XCD(bid)=y%8).
// Phase B: bid<ngemm GEMM tile (y=bid%24 fast -> XCD=y%8 owns W panel y, dedup);
//   [ngemm, ngemm+nx) affinity tiles.
__launch_bounds__(256, 2)
__global__ void k_all(const float* __restrict__ tokens, const float* __restrict__ fp,
                      const float* __restrict__ alpha,
                      const float* __restrict__ gw1, const float* __restrict__ gb1,
                      const float* __restrict__ gw2, const float* __restrict__ gb2,
                      const float* __restrict__ wq, const float* __restrict__ wk,
                      const float* __restrict__ wv, const float* __restrict__ penta,
                      bf16* __restrict__ wqkvb, float* __restrict__ cwp,
                      float* __restrict__ mask_out, bf16* __restrict__ Fs,
                      float* __restrict__ out, float* __restrict__ aff,
                      unsigned* bar, int p, int M, int Mpad, int nblk) {
    __shared__ __align__(16) char ubuf[33280];   // gate F[32][520] / GEMM As+Bs 32KB / aff cwt 16KB
    __shared__ int trow[32];
    __shared__ float scl[32];
    __shared__ float part[32][4];
    __shared__ int sOffs[256];
    __shared__ unsigned short sBits[256];
    __shared__ int wsum[4];
    __shared__ float sd[5][32];
    __shared__ float red[5][4];

    const int bid = blockIdx.x, t = threadIdx.x;
    const int wave = t >> 6, lane = t & 63;
    const int fr = lane & 15, fq = lane >> 4;
    const int ngate = Mpad / 32;
    const int nx = Mpad / 128;
    const int ngemm = nx * 24;
    const int cwbase = ngate + 2;
    const int cvbase = (ngate + 41) & ~7;

    // ================= phase A =================
    if (bid < ngate) {
        // ---------------- gate block (32 rows) ----------------
        bf16 (*F)[520] = (bf16(*)[520])ubuf;
        const int m0 = bid * 32;
        {
            int base = t * 16;
            unsigned bits = 0;
            int cnt = 0;
#pragma unroll
            for (int i = 0; i < 16; i++) {
                float v = fp[base + i];
                bool m = (v >= 0.375f) && (v < 0.5f);
                bits |= ((unsigned)m) << i;
                cnt += (int)m;
            }
            int incl = cnt;
#pragma unroll
            for (int d = 1; d < 64; d <<= 1) {
                int n = __shfl_up(incl, d);
                if (lane >= d) incl += n;
            }
            if (lane == 63) wsum[wave] = incl;
            __syncthreads();
            int wbase = 0;
            for (int w = 0; w < 4; w++) if (w < wave) wbase += wsum[w];
            sOffs[t] = wbase + incl - cnt;
            sBits[t] = (unsigned short)bits;
        }
        __syncthreads();
        if (t < 32) {
            int m = m0 + t;
            int r = -1;
            if (m < M) {
                int b = m / p, j = m - b * p;
                int lo = 0, hi = 255;
                while (lo < hi) { int mid = (lo + hi + 1) >> 1; if (sOffs[mid] <= j) lo = mid; else hi = mid - 1; }
                int jj = j - sOffs[lo];
                unsigned bt = sBits[lo];
                int pos = 0;
#pragma unroll
                for (int bit = 0; bit < 16; bit++) {
                    if ((bt >> bit) & 1) { if (jj == 0) { pos = bit; break; } jj--; }
                }
                r = b * P_TOK + lo * 16 + pos;
            }
            trow[t] = r;
        }
        __syncthreads();
#pragma unroll
        for (int it = 0; it < 16; it++) {
            int r = it * 2 + (t >> 7);
            int c4 = (t & 127) * 4;
            int tr = trow[r];
            float4 v = {0.f, 0.f, 0.f, 0.f};
            if (tr >= 0) v = *(const float4*)(tokens + (size_t)tr * FULL_DIM + S0 + c4);
            bf16x4 b = { (bf16)v.x, (bf16)v.y, (bf16)v.z, (bf16)v.w };
            *(bf16x4*)(&F[r][c4]) = b;
        }
        __syncthreads();
        f32x4 acc[2][2];
#pragma unroll
        for (int i = 0; i < 2; i++)
#pragma unroll
            for (int j = 0; j < 2; j++) acc[i][j] = (f32x4){0.f, 0.f, 0.f, 0.f};
        const int n0 = wave * 32 + fr;
#pragma unroll
        for (int k0 = 0; k0 < 512; k0 += 64) {
#pragma unroll
            for (int ks = 0; ks < 2; ks++) {
                const int ko = k0 + ks * 32 + fq * 8;
                bf16x8 b0 = cvt8(gw1 + (size_t)n0 * 512 + ko);
                bf16x8 b1 = cvt8(gw1 + (size_t)(n0 + 16) * 512 + ko);
                bf16x8 a0 = *(const bf16x8*)(&F[fr][ko]);
                bf16x8 a1 = *(const bf16x8*)(&F[16 + fr][ko]);
                acc[0][0] = __builtin_amdgcn_mfma_f32_16x16x32_bf16(a0, b0, acc[0][0], 0, 0, 0);
                acc[0][1] = __builtin_amdgcn_mfma_f32_16x16x32_bf16(a0, b1, acc[0][1], 0, 0, 0);
                acc[1][0] = __builtin_amdgcn_mfma_f32_16x16x32_bf16(a1, b0, acc[1][0], 0, 0, 0);
                acc[1][1] = __builtin_amdgcn_mfma_f32_16x16x32_bf16(a1, b1, acc[1][1], 0, 0, 0);
            }
        }
        {
            float s[2][4];
#pragma unroll
            for (int mi = 0; mi < 2; mi++)
#pragma unroll
                for (int r = 0; r < 4; r++) s[mi][r] = 0.f;
#pragma unroll
            for (int ni = 0; ni < 2; ni++) {
                int col = wave * 32 + ni * 16 + fr;
                float bias = gb1[col], g2 = gw2[col];
#pragma unroll
                for (int mi = 0; mi < 2; mi++)
#pragma unroll
                    for (int r = 0; r < 4; r++) {
                        float v = acc[mi][ni][r] + bias;
                        float h = 0.5f * v * (1.0f + erff(v * 0.70710678118f));
                        s[mi][r] += h * g2;
                    }
            }
#pragma unroll
            for (int mi = 0; mi < 2; mi++)
#pragma unroll
                for (int r = 0; r < 4; r++) {
                    float v = s[mi][r];
                    v += __shfl_xor(v, 1); v += __shfl_xor(v, 2);
                    v += __shfl_xor(v, 4); v += __shfl_xor(v, 8);
                    s[mi][r] = v;
                }
            if (fr == 0) {
#pragma unroll
                for (int mi = 0; mi < 2; mi++)
#pragma unroll
                    for (int r = 0; r < 4; r++)
                        part[mi * 16 + fq * 4 + r][wave] = s[mi][r];
            }
        }
        __syncthreads();
        if (t < 32) {
            float ssum = part[t][0] + part[t][1] + part[t][2] + part[t][3];
            float aw = 1.0f / (1.0f + expf(-alpha[0]));
            float gt = 1.0f / (1.0f + expf(-(ssum + gb2[0])));
            scl[t] = gt * aw + (1.0f - aw);
        }
        __syncthreads();
#pragma unroll
        for (int it = 0; it < 16; it++) {
            int r = it * 2 + (t >> 7);
            int c4 = (t & 127) * 4;
            bf16x4 b = *(const bf16x4*)(&F[r][c4]);
            float sc = scl[r];
            bf16x4 o = { (bf16)((float)b[0] * sc), (bf16)((float)b[1] * sc),
                         (bf16)((float)b[2] * sc), (bf16)((float)b[3] * sc) };
            *(bf16x4*)(Fs + (size_t)(m0 + r) * 512 + c4) = o;
        }
    } else if (bid == ngate) {
        // ---------------- mask ----------------
        int base = t * 16;
#pragma unroll
        for (int i = 0; i < 16; i++) {
            float v = fp[base + i];
            mask_out[base + i] = ((v >= 0.375f) && (v < 0.5f)) ? 1.0f : 0.0f;
        }
    } else if (bid >= cwbase && bid < cwbase + NCW) {
        // ---------------- cw partial (32 d-values) ----------------
        const int cb = bid - cwbase;
        const int d0 = cb * 32;
#pragma unroll
        for (int v = 0; v < 5; v++) {
            float s = 0.f;
#pragma unroll
            for (int i = 0; i < 4; i++) { float x = penta[v * 1024 + t + i * 256]; s += x * x; }
            for (int d = 32; d; d >>= 1) s += __shfl_xor(s, d);
            if (lane == 0) red[v][wave] = s;
        }
        __syncthreads();
        for (int e = t; e < 5 * 32; e += 256) {
            int v = e >> 5, dd = e & 31;
            float inv = rsqrtf(red[v][0] + red[v][1] + red[v][2] + red[v][3]);
            sd[v][dd] = penta[v * 1024 + d0 + dd] * inv;
        }
        __syncthreads();
#pragma unroll
        for (int pass = 0; pass < 2; pass++) {
            int col = pass * 256 + t;
            float aK[5] = {0, 0, 0, 0, 0}, aQ[5] = {0, 0, 0, 0, 0};
            for (int d = 0; d < 32; d += 4) {
#pragma unroll
                for (int uu = 0; uu < 4; uu++) {
                    float kv = wk[(size_t)(d0 + d + uu) * 512 + col];
                    float qv = wq[(size_t)(d0 + d + uu) * 512 + col];
#pragma unroll
                    for (int v = 0; v < 5; v++) {
                        float dv = sd[v][d + uu];
                        aK[v] += dv * kv;
                        aQ[v] += dv * qv;
                    }
                }
            }
#pragma unroll
            for (int v = 0; v < 5; v++) {
                cwp[((size_t)v * NCW + cb) * 512 + col] = aK[v];
                cwp[((size_t)(5 + v) * NCW + cb) * 512 + col] = aQ[v];
            }
        }
    } else if (bid >= cvbase && bid < cvbase + 24) {
        // ---------------- convert W slab y (XCD-aligned: bid%8 == y%8) ----------------
        int y = bid - cvbase;
        const float* src = (y < 8) ? wq : (y < 16 ? wk : wv);
        src += (size_t)(y & 7) * 128 * 512;
        bf16* dst = wqkvb + (size_t)y * 128 * 512;
#pragma unroll 4
        for (int it = 0; it < 64; it++) {
            int i = it * 1024 + t * 4;
            float4 v = *(const float4*)(src + i);
            bf16x4 b = { (bf16)v.x, (bf16)v.y, (bf16)v.z, (bf16)v.w };
            *(bf16x4*)(dst + i) = b;
        }
    }

    // ================= grid barrier (all blocks resident by __launch_bounds__(256,2)) =================
    __syncthreads();
    if (t == 0) {
        __threadfence();                      // flush this XCD's L2 (release)
        atomicAdd(bar, 1u);
        while (__hip_atomic_load(bar, __ATOMIC_RELAXED, __HIP_MEMORY_SCOPE_AGENT) < (unsigned)nblk)
            __builtin_amdgcn_s_sleep(8);
        __threadfence();                      // acquire
    }
    __syncthreads();

    // ================= phase B =================
    if (bid < ngemm) {
        // ---------------- GEMM tile 128x128, BK=32, swizzled, counted vmcnt ----------------
        const int y = bid % 24, x = bid / 24;
        const int m0 = x * 128, n0g = y * 128;
        const int wr = wave >> 1, wc = wave & 1;
        bf16* As = (bf16*)ubuf;               // [2][128*32]
        bf16* Bs = (bf16*)(ubuf + 16384);     // [2][128*32]

        f32x4 acc[4][4];
#pragma unroll
        for (int i = 0; i < 4; i++)
#pragma unroll
            for (int j = 0; j < 4; j++) acc[i][j] = (f32x4){0.f, 0.f, 0.f, 0.f};

        const int lr4 = lane >> 2;                     // 0..15 (row within 16-row group)
        const int js = (lane & 3) ^ (lr4 & 3);         // swizzled source chunk
        const bf16* gaL = Fs    + (size_t)(m0  + wave * 32 + lr4) * 512 + js * 8;
        const bf16* gbL = wqkvb + (size_t)(n0g + wave * 32 + lr4) * 512 + js * 8;
        const int xr3 = fr & 3;

#define STAGE(buf, ko)                                                      \
        gl_lds16(gaL + (ko),            As + (buf) * 4096 + (wave * 32) * 32);        \
        gl_lds16(gaL + (ko) + 16 * 512, As + (buf) * 4096 + (wave * 32 + 16) * 32);   \
        gl_lds16(gbL + (ko),            Bs + (buf) * 4096 + (wave * 32) * 32);        \
        gl_lds16(gbL + (ko) + 16 * 512, Bs + (buf) * 4096 + (wave * 32 + 16) * 32);

#define COMPUTE(buf)                                                                     \
        {                                                                                \
            const int co = (fq ^ xr3) * 8;                                               \
            bf16x8 af[4], bw[4];                                                         \
            _Pragma("unroll")                                                            \
            for (int mi = 0; mi < 4; mi++)                                               \
                af[mi] = *(const bf16x8*)(As + (buf) * 4096 + (wr * 64 + mi * 16 + fr) * 32 + co); \
            _Pragma("unroll")                                                            \
            for (int ni = 0; ni < 4; ni++)                                               \
                bw[ni] = *(const bf16x8*)(Bs + (buf) * 4096 + (wc * 64 + ni * 16 + fr) * 32 + co); \
            _Pragma("unroll")                                                            \
            for (int mi = 0; mi < 4; mi++)                                               \
                _Pragma("unroll")                                                        \
                for (int ni = 0; ni < 4; ni++)                                           \
                    acc[mi][ni] = __builtin_amdgcn_mfma_f32_16x16x32_bf16(af[mi], bw[ni], acc[mi][ni], 0, 0, 0); \
        }

        STAGE(0, 0);
        int cur = 0;
#pragma unroll 1
        for (int kt = 0; kt < 16; kt++) {
            if (kt < 15) {
                STAGE(cur ^ 1, (kt + 1) * 32);
                asm volatile("s_waitcnt vmcnt(4)" ::: "memory");   // stage kt's 4 landed
            } else {
                asm volatile("s_waitcnt vmcnt(0)" ::: "memory");
            }
            __builtin_amdgcn_s_barrier();
            COMPUTE(cur);
            __builtin_amdgcn_s_barrier();
            cur ^= 1;
        }
#undef STAGE
#undef COMPUTE

        const int z = y >> 3;
        const int nb = (y & 7) * 128;
        float* obase = out + (size_t)z * M * EXPERT_DIM;
#pragma unroll
        for (int mi = 0; mi < 4; mi++)
#pragma unroll
            for (int ni = 0; ni < 4; ni++) {
                int col = nb + wc * 64 + ni * 16 + fr;
#pragma unroll
                for (int r = 0; r < 4; r++) {
                    int row = m0 + wr * 64 + mi * 16 + fq * 4 + r;
                    if (row < M) obase[(size_t)row * EXPERT_DIM + col] = acc[mi][ni][r];
                }
            }
    } else if (bid < ngemm + nx) {
        // ---------------- affinity tile (128 rows) ----------------
        const int ax = bid - ngemm;
        bf16* cwt = (bf16*)ubuf;
        for (int e = t; e < 16 * 512; e += 256) {
            int v = e >> 9, c = e & 511;
            float s = 0.f;
            if (v < 10) {
#pragma unroll
                for (int cb = 0; cb < NCW; cb++)
                    s += cwp[((size_t)v * NCW + cb) * 512 + c];
            }
            int byte = v * 1024 + ((((c >> 3) ^ (v & 7)) << 4)) + (c & 7) * 2;
            *(bf16*)((char*)cwt + byte) = (bf16)s;
        }
        __syncthreads();
        const int m0w = ax * 128 + wave * 32;
        f32x4 acc0 = (f32x4){0.f, 0.f, 0.f, 0.f};
        f32x4 acc1 = (f32x4){0.f, 0.f, 0.f, 0.f};
        for (int k0 = 0; k0 < 512; k0 += 32) {
            int chunk = (k0 >> 3) + fq;
            bf16x8 b = *(const bf16x8*)((char*)cwt + fr * 1024 + ((chunk ^ (fr & 7)) << 4));
            bf16x8 a0 = *(const bf16x8*)(Fs + (size_t)(m0w + fr) * 512 + k0 + fq * 8);
            bf16x8 a1 = *(const bf16x8*)(Fs + (size_t)(m0w + 16 + fr) * 512 + k0 + fq * 8);
            acc0 = __builtin_amdgcn_mfma_f32_16x16x32_bf16(a0, b, acc0, 0, 0, 0);
            acc1 = __builtin_amdgcn_mfma_f32_16x16x32_bf16(a1, b, acc1, 0, 0, 0);
        }
        if (fr < 10) {
#pragma unroll
            for (int r = 0; r < 4; r++) {
                int m = m0w + fq * 4 + r;
                if (m < M) aff[(size_t)fr * M + m] = acc0[r];
                m += 16;
                if (m < M) aff[(size_t)fr * M + m] = acc1[r];
            }
        }
    }
}

extern "C" void kernel_launch(void* const* d_in, const int* in_sizes, int n_in,
                              void* d_out, int out_size, void* d_ws, size_t ws_size,
                              hipStream_t stream) {
    const float* tokens = (const float*)d_in[0];
    const float* fps    = (const float*)d_in[1];
    const float* alpha  = (const float*)d_in[2];
    const float* gw1    = (const float*)d_in[3];
    const float* gb1    = (const float*)d_in[4];
    const float* gw2    = (const float*)d_in[5];
    const float* gb2    = (const float*)d_in[6];
    const float* wq     = (const float*)d_in[7];
    const float* wk     = (const float*)d_in[8];
    const float* wv     = (const float*)d_in[9];
    const float* penta  = (const float*)d_in[10];
    float* out = (float*)d_out;

    int p = (out_size - P_TOK) / (3 * BATCH * EXPERT_DIM + 2 * 5 * BATCH);  // 12328
    if (p <= 0) return;
    int M = BATCH * p;
    int Mpad = (M + 127) & ~127;

    char* ws = (char*)d_ws;
    size_t off = 0;
    unsigned* bar  = (unsigned*)(ws + off); off += 256;
    bf16*  wqkvb = (bf16*)(ws + off);  off += (size_t)3 * EXPERT_DIM * SLICE * 2;
    float* cwp   = (float*)(ws + off); off += (size_t)NCW * 10 * 512 * 4;
    bf16*  Fs    = (bf16*)(ws + off);  off += (size_t)Mpad * SLICE * 2;
    (void)ws_size;

    float* aff_out  = out + (size_t)3 * M * EXPERT_DIM;
    float* mask_out = aff_out + (size_t)10 * M;

    int ngate = Mpad / 32;
    int nx = Mpad / 128;
    int ngemm = nx * 24;
    int cvbase = (ngate + 41) & ~7;
    int nblk = ngemm + nx;
    if (cvbase + 24 > nblk) nblk = cvbase + 24;

    hipMemsetAsync(bar, 0, 256, stream);
    k_all<<<nblk, 256, 0, stream>>>(tokens, fps, alpha, gw1, gb1, gw2, gb2,
                                    wq, wk, wv, penta, wqkvb, cwp, mask_out, Fs,
                                    out, aff_out, bar, p, M, Mpad, nblk);
}

// Round 13
// 57.566 us; speedup vs baseline: 1.5318x; 1.5318x over previous
//
#include <hip/hip_runtime.h>
#include <hip/hip_bf16.h>

#define FULL_DIM 4096
#define EXPERT_DIM 1024
#define SLICE 512
#define S0 (3*SLICE)
#define GATE_HID 128
#define P_TOK 4096
#define BATCH 4
#define NCONV 192    // 3*1024*512 elems / (256 thr * 4 * 8)
#define NCW 32       // cw partial blocks (32 d-values each)

typedef __bf16 bf16;
typedef __bf16 bf16x4 __attribute__((ext_vector_type(4)));
typedef __bf16 bf16x8 __attribute__((ext_vector_type(8)));
typedef float f32x4 __attribute__((ext_vector_type(4)));

__device__ inline void gl_lds16(const void* g, void* l) {
    __builtin_amdgcn_global_load_lds((const __attribute__((address_space(1))) void*)g,
                                     (__attribute__((address_space(3))) void*)l, 16, 0, 0);
}

__device__ inline bf16x8 cvt8(const float* src) {
    float4 a = *(const float4*)(src);
    float4 b = *(const float4*)(src + 4);
    bf16x8 w = { (bf16)a.x, (bf16)a.y, (bf16)a.z, (bf16)a.w,
                 (bf16)b.x, (bf16)b.y, (bf16)b.z, (bf16)b.w };
    return w;
}

// ============ kernel 1: gate + mask + cw partials + weight converts (R9 slim) ============
__launch_bounds__(256)
__global__ void k_front(const float* __restrict__ tokens, const float* __restrict__ fp,
                        const float* __restrict__ alpha,
                        const float* __restrict__ gw1, const float* __restrict__ gb1,
                        const float* __restrict__ gw2, const float* __restrict__ gb2,
                        const float* __restrict__ wq, const float* __restrict__ wk,
                        const float* __restrict__ wv, const float* __restrict__ penta,
                        bf16* __restrict__ wqkvb, float* __restrict__ cwp,
                        float* __restrict__ mask_out, bf16* __restrict__ Fs,
                        int p, int M, int ngate) {
    __shared__ bf16 F[32][520];
    __shared__ int trow[32];
    __shared__ float scl[32];
    __shared__ float part[32][4];
    __shared__ int sOffs[256];
    __shared__ unsigned short sBits[256];
    __shared__ int wsum[4];
    __shared__ float sd[5][32];
    __shared__ float red[5][4];
    const int bid = blockIdx.x, t = threadIdx.x;
    const int wave = t >> 6, lane = t & 63;

    if (bid < ngate) {
        const int fr = lane & 15, fq = lane >> 4;
        const int m0 = bid * 32;
        {
            int base = t * 16;
            unsigned bits = 0;
            int cnt = 0;
#pragma unroll
            for (int i = 0; i < 16; i++) {
                float v = fp[base + i];
                bool m = (v >= 0.375f) && (v < 0.5f);
                bits |= ((unsigned)m) << i;
                cnt += (int)m;
            }
            int incl = cnt;
#pragma unroll
            for (int d = 1; d < 64; d <<= 1) {
                int n = __shfl_up(incl, d);
                if (lane >= d) incl += n;
            }
            if (lane == 63) wsum[wave] = incl;
            __syncthreads();
            int wbase = 0;
            for (int w = 0; w < 4; w++) if (w < wave) wbase += wsum[w];
            sOffs[t] = wbase + incl - cnt;
            sBits[t] = (unsigned short)bits;
        }
        __syncthreads();
        if (t < 32) {
            int m = m0 + t;
            int r = -1;
            if (m < M) {
                int b = m / p, j = m - b * p;
                int lo = 0, hi = 255;
                while (lo < hi) { int mid = (lo + hi + 1) >> 1; if (sOffs[mid] <= j) lo = mid; else hi = mid - 1; }
                int jj = j - sOffs[lo];
                unsigned bt = sBits[lo];
                int pos = 0;
#pragma unroll
                for (int bit = 0; bit < 16; bit++) {
                    if ((bt >> bit) & 1) { if (jj == 0) { pos = bit; break; } jj--; }
                }
                r = b * P_TOK + lo * 16 + pos;
            }
            trow[t] = r;
        }
        __syncthreads();
#pragma unroll
        for (int it = 0; it < 16; it++) {
            int r = it * 2 + (t >> 7);
            int c4 = (t & 127) * 4;
            int tr = trow[r];
            float4 v = {0.f, 0.f, 0.f, 0.f};
            if (tr >= 0) v = *(const float4*)(tokens + (size_t)tr * FULL_DIM + S0 + c4);
            bf16x4 b = { (bf16)v.x, (bf16)v.y, (bf16)v.z, (bf16)v.w };
            *(bf16x4*)(&F[r][c4]) = b;
        }
        __syncthreads();
        f32x4 acc[2][2];
#pragma unroll
        for (int i = 0; i < 2; i++)
#pragma unroll
            for (int j = 0; j < 2; j++) acc[i][j] = (f32x4){0.f, 0.f, 0.f, 0.f};
        const int n0 = wave * 32 + fr;
#pragma unroll
        for (int k0 = 0; k0 < 512; k0 += 64) {
#pragma unroll
            for (int ks = 0; ks < 2; ks++) {
                const int ko = k0 + ks * 32 + fq * 8;
                bf16x8 b0 = cvt8(gw1 + (size_t)n0 * 512 + ko);
                bf16x8 b1 = cvt8(gw1 + (size_t)(n0 + 16) * 512 + ko);
                bf16x8 a0 = *(const bf16x8*)(&F[fr][ko]);
                bf16x8 a1 = *(const bf16x8*)(&F[16 + fr][ko]);
                acc[0][0] = __builtin_amdgcn_mfma_f32_16x16x32_bf16(a0, b0, acc[0][0], 0, 0, 0);
                acc[0][1] = __builtin_amdgcn_mfma_f32_16x16x32_bf16(a0, b1, acc[0][1], 0, 0, 0);
                acc[1][0] = __builtin_amdgcn_mfma_f32_16x16x32_bf16(a1, b0, acc[1][0], 0, 0, 0);
                acc[1][1] = __builtin_amdgcn_mfma_f32_16x16x32_bf16(a1, b1, acc[1][1], 0, 0, 0);
            }
        }
        {
            float s[2][4];
#pragma unroll
            for (int mi = 0; mi < 2; mi++)
#pragma unroll
                for (int r = 0; r < 4; r++) s[mi][r] = 0.f;
#pragma unroll
            for (int ni = 0; ni < 2; ni++) {
                int col = wave * 32 + ni * 16 + fr;
                float bias = gb1[col], g2 = gw2[col];
#pragma unroll
                for (int mi = 0; mi < 2; mi++)
#pragma unroll
                    for (int r = 0; r < 4; r++) {
                        float v = acc[mi][ni][r] + bias;
                        float h = 0.5f * v * (1.0f + erff(v * 0.70710678118f));
                        s[mi][r] += h * g2;
                    }
            }
#pragma unroll
            for (int mi = 0; mi < 2; mi++)
#pragma unroll
                for (int r = 0; r < 4; r++) {
                    float v = s[mi][r];
                    v += __shfl_xor(v, 1); v += __shfl_xor(v, 2);
                    v += __shfl_xor(v, 4); v += __shfl_xor(v, 8);
                    s[mi][r] = v;
                }
            if (fr == 0) {
#pragma unroll
                for (int mi = 0; mi < 2; mi++)
#pragma unroll
                    for (int r = 0; r < 4; r++)
                        part[mi * 16 + fq * 4 + r][wave] = s[mi][r];
            }
        }
        __syncthreads();
        if (t < 32) {
            float ssum = part[t][0] + part[t][1] + part[t][2] + part[t][3];
            float aw = 1.0f / (1.0f + expf(-alpha[0]));
            float gt = 1.0f / (1.0f + expf(-(ssum + gb2[0])));
            scl[t] = gt * aw + (1.0f - aw);
        }
        __syncthreads();
#pragma unroll
        for (int it = 0; it < 16; it++) {
            int r = it * 2 + (t >> 7);
            int c4 = (t & 127) * 4;
            bf16x4 b = *(const bf16x4*)(&F[r][c4]);
            float sc = scl[r];
            bf16x4 o = { (bf16)((float)b[0] * sc), (bf16)((float)b[1] * sc),
                         (bf16)((float)b[2] * sc), (bf16)((float)b[3] * sc) };
            *(bf16x4*)(Fs + (size_t)(m0 + r) * 512 + c4) = o;
        }
        return;
    }
    if (bid == ngate) {
        int base = t * 16;
#pragma unroll
        for (int i = 0; i < 16; i++) {
            float v = fp[base + i];
            mask_out[base + i] = ((v >= 0.375f) && (v < 0.5f)) ? 1.0f : 0.0f;
        }
        return;
    }
    if (bid <= ngate + NCW) {
        const int cb = bid - (ngate + 1);
        const int d0 = cb * 32;
#pragma unroll
        for (int v = 0; v < 5; v++) {
            float s = 0.f;
#pragma unroll
            for (int i = 0; i < 4; i++) { float x = penta[v * 1024 + t + i * 256]; s += x * x; }
            for (int d = 32; d; d >>= 1) s += __shfl_xor(s, d);
            if (lane == 0) red[v][wave] = s;
        }
        __syncthreads();
        for (int e = t; e < 5 * 32; e += 256) {
            int v = e >> 5, dd = e & 31;
            float inv = rsqrtf(red[v][0] + red[v][1] + red[v][2] + red[v][3]);
            sd[v][dd] = penta[v * 1024 + d0 + dd] * inv;
        }
        __syncthreads();
#pragma unroll
        for (int pass = 0; pass < 2; pass++) {
            int col = pass * 256 + t;
            float aK[5] = {0, 0, 0, 0, 0}, aQ[5] = {0, 0, 0, 0, 0};
            for (int d = 0; d < 32; d += 4) {
#pragma unroll
                for (int uu = 0; uu < 4; uu++) {
                    float kv = wk[(size_t)(d0 + d + uu) * 512 + col];
                    float qv = wq[(size_t)(d0 + d + uu) * 512 + col];
#pragma unroll
                    for (int v = 0; v < 5; v++) {
                        float dv = sd[v][d + uu];
                        aK[v] += dv * kv;
                        aQ[v] += dv * qv;
                    }
                }
            }
#pragma unroll
            for (int v = 0; v < 5; v++) {
                cwp[((size_t)v * NCW + cb) * 512 + col] = aK[v];
                cwp[((size_t)(5 + v) * NCW + cb) * 512 + col] = aQ[v];
            }
        }
        return;
    }
    {
        int ci = bid - (ngate + 1 + NCW);
        int base = ci * 8192 + t * 4;
        const float* src = (base < 524288) ? wq : (base < 2 * 524288 ? wk : wv);
        const int arr = base & 524287;
#pragma unroll
        for (int q = 0; q < 8; q++) {
            int i = arr + q * 1024;
            float4 v = *(const float4*)(src + i);
            bf16x4 b = { (bf16)v.x, (bf16)v.y, (bf16)v.z, (bf16)v.w };
            *(bf16x4*)(wqkvb + (base < 524288 ? 0 : (base < 2 * 524288 ? 524288 : 2 * 524288)) + i) = b;
        }
    }
}

// ============ kernel 2: QKV GEMM 128x128, BK=32, 32KB LDS (4 blocks/CU), y-fast XCD dedup ============
// 1D grid, bid < nx*24: GEMM tile y=bid%24, x=bid/24 (24%8==0 -> all consumers of W panel y
// land on XCD y%8: W deduped, per-XCD L2 set ~2.4MB). Tail nx blocks: affinity.
__launch_bounds__(256)
__global__ void k_qkv(const bf16* __restrict__ A, const bf16* __restrict__ W,
                      const float* __restrict__ cwp, float* __restrict__ out,
                      float* __restrict__ aff, int M, int nx) {
    __shared__ bf16 As[2][128 * 32];   // 8 KB each
    __shared__ bf16 Bs[2][128 * 32];   // 8 KB each
    const int t = threadIdx.x, wave = t >> 6, lane = t & 63;
    const int fr = lane & 15, fq = lane >> 4;
    const int bid = blockIdx.x;
    const int ngemm = nx * 24;

    if (bid >= ngemm) {
        // ---- affinity tile (128 rows) ----
        const int ax = bid - ngemm;
        bf16* cwt = (bf16*)As;
        for (int e = t; e < 16 * 512; e += 256) {
            int v = e >> 9, c = e & 511;
            float s = 0.f;
            if (v < 10) {
#pragma unroll
                for (int cb = 0; cb < NCW; cb++)
                    s += cwp[((size_t)v * NCW + cb) * 512 + c];
            }
            int byte = v * 1024 + ((((c >> 3) ^ (v & 7)) << 4)) + (c & 7) * 2;
            *(bf16*)((char*)cwt + byte) = (bf16)s;
        }
        __syncthreads();
        const int m0w = ax * 128 + wave * 32;
        f32x4 acc0 = (f32x4){0.f, 0.f, 0.f, 0.f};
        f32x4 acc1 = (f32x4){0.f, 0.f, 0.f, 0.f};
        for (int k0 = 0; k0 < 512; k0 += 32) {
            int chunk = (k0 >> 3) + fq;
            bf16x8 b = *(const bf16x8*)((char*)cwt + fr * 1024 + ((chunk ^ (fr & 7)) << 4));
            bf16x8 a0 = *(const bf16x8*)(A + (size_t)(m0w + fr) * 512 + k0 + fq * 8);
            bf16x8 a1 = *(const bf16x8*)(A + (size_t)(m0w + 16 + fr) * 512 + k0 + fq * 8);
            acc0 = __builtin_amdgcn_mfma_f32_16x16x32_bf16(a0, b, acc0, 0, 0, 0);
            acc1 = __builtin_amdgcn_mfma_f32_16x16x32_bf16(a1, b, acc1, 0, 0, 0);
        }
        if (fr < 10) {
#pragma unroll
            for (int r = 0; r < 4; r++) {
                int m = m0w + fq * 4 + r;
                if (m < M) aff[(size_t)fr * M + m] = acc0[r];
                m += 16;
                if (m < M) aff[(size_t)fr * M + m] = acc1[r];
            }
        }
        return;
    }

    // ---- GEMM tile ----
    const int y = bid % 24, x = bid / 24;
    const int m0 = x * 128, n0 = y * 128;
    const int wr = wave >> 1, wc = wave & 1;

    f32x4 acc[4][4];
#pragma unroll
    for (int i = 0; i < 4; i++)
#pragma unroll
        for (int j = 0; j < 4; j++) acc[i][j] = (f32x4){0.f, 0.f, 0.f, 0.f};

    // store-side swizzle: row r (16-row groups), 4 chunks of 16B; key(r) = (r ^ (r>>2)) & 3
    const int lr = lane >> 2;                       // 0..15
    const int key = (lr ^ (lr >> 2)) & 3;
    const int js = (lane & 3) ^ key;                // pre-swizzled source chunk
    const bf16* gaL = A + (size_t)(m0 + wave * 32 + lr) * 512 + js * 8;
    const bf16* gbL = W + (size_t)(n0 + wave * 32 + lr) * 512 + js * 8;
    const int kr = (fr ^ (fr >> 2)) & 3;            // read-side key (row ≡ fr mod 16)

    // 4 gl_lds per wave per stage: 2 A (16 rows each), 2 B
#define STAGE(buf, ko)                                                \
    gl_lds16(gaL + (ko),            &As[buf][(wave * 2 + 0) * 512]);  \
    gl_lds16(gaL + (ko) + 16 * 512, &As[buf][(wave * 2 + 1) * 512]);  \
    gl_lds16(gbL + (ko),            &Bs[buf][(wave * 2 + 0) * 512]);  \
    gl_lds16(gbL + (ko) + 16 * 512, &Bs[buf][(wave * 2 + 1) * 512]);

#define COMPUTE(buf)                                                                      \
    {                                                                                     \
        const int co = ((fq ^ kr)) * 8;                                                   \
        bf16x8 af[4], bw[4];                                                              \
        _Pragma("unroll")                                                                 \
        for (int mi = 0; mi < 4; mi++)                                                    \
            af[mi] = *(const bf16x8*)(&As[buf][(wr * 64 + mi * 16 + fr) * 32 + co]);      \
        _Pragma("unroll")                                                                 \
        for (int ni = 0; ni < 4; ni++)                                                    \
            bw[ni] = *(const bf16x8*)(&Bs[buf][(wc * 64 + ni * 16 + fr) * 32 + co]);      \
        _Pragma("unroll")                                                                 \
        for (int mi = 0; mi < 4; mi++)                                                    \
            _Pragma("unroll")                                                             \
            for (int ni = 0; ni < 4; ni++)                                                \
                acc[mi][ni] = __builtin_amdgcn_mfma_f32_16x16x32_bf16(af[mi], bw[ni], acc[mi][ni], 0, 0, 0); \
    }

    STAGE(0, 0);
    int cur = 0;
#pragma unroll 1
    for (int kt = 0; kt < 16; kt++) {
        if (kt < 15) {
            STAGE(cur ^ 1, (kt + 1) * 32);
            asm volatile("s_waitcnt vmcnt(4)" ::: "memory");   // stage kt's 4 landed
        } else {
            asm volatile("s_waitcnt vmcnt(0)" ::: "memory");
        }
        __builtin_amdgcn_s_barrier();
        COMPUTE(cur);
        __builtin_amdgcn_s_barrier();
        cur ^= 1;
    }
#undef STAGE
#undef COMPUTE

    const int z = y >> 3;
    const int nb = (y & 7) * 128;
    float* obase = out + (size_t)z * M * EXPERT_DIM;
#pragma unroll
    for (int mi = 0; mi < 4; mi++)
#pragma unroll
        for (int ni = 0; ni < 4; ni++) {
            int col = nb + wc * 64 + ni * 16 + fr;
#pragma unroll
            for (int r = 0; r < 4; r++) {
                int row = m0 + wr * 64 + mi * 16 + fq * 4 + r;
                if (row < M) obase[(size_t)row * EXPERT_DIM + col] = acc[mi][ni][r];
            }
        }
}

extern "C" void kernel_launch(void* const* d_in, const int* in_sizes, int n_in,
                              void* d_out, int out_size, void* d_ws, size_t ws_size,
                              hipStream_t stream) {
    const float* tokens = (const float*)d_in[0];
    const float* fps    = (const float*)d_in[1];
    const float* alpha  = (const float*)d_in[2];
    const float* gw1    = (const float*)d_in[3];
    const float* gb1    = (const float*)d_in[4];
    const float* gw2    = (const float*)d_in[5];
    const float* gb2    = (const float*)d_in[6];
    const float* wq     = (const float*)d_in[7];
    const float* wk     = (const float*)d_in[8];
    const float* wv     = (const float*)d_in[9];
    const float* penta  = (const float*)d_in[10];
    float* out = (float*)d_out;

    int p = (out_size - P_TOK) / (3 * BATCH * EXPERT_DIM + 2 * 5 * BATCH);  // 12328
    if (p <= 0) return;
    int M = BATCH * p;
    int Mpad = (M + 127) & ~127;
    int ngate = Mpad / 32;
    int nx = Mpad / 128;

    char* ws = (char*)d_ws;
    size_t off = 0;
    bf16*  wqkvb = (bf16*)(ws + off);  off += (size_t)3 * EXPERT_DIM * SLICE * 2;
    float* cwp   = (float*)(ws + off); off += (size_t)NCW * 10 * 512 * 4;
    bf16*  Fs    = (bf16*)(ws + off);  off += (size_t)Mpad * SLICE * 2;
    (void)ws_size;

    float* aff_out  = out + (size_t)3 * M * EXPERT_DIM;
    float* mask_out = aff_out + (size_t)10 * M;

    k_front<<<ngate + 1 + NCW + NCONV, 256, 0, stream>>>(
        tokens, fps, alpha, gw1, gb1, gw2, gb2, wq, wk, wv, penta,
        wqkvb, cwp, mask_out, Fs, p, M, ngate);
    k_qkv<<<nx * 24 + nx, 256, 0, stream>>>(Fs, wqkvb, cwp, out, aff_out, M, nx);
}